// Round 7
// baseline (72.683 us; speedup 1.0000x reference)
//
#include <hip/hip_runtime.h>
#include <hip/hip_bf16.h>
#include <math.h>

#define BB 16
#define NN 256
#define LL 1024
#define DD 256

constexpr float LN_EPS = 1e-5f;
constexpr float NEG_SLOPE = 0.01f;

typedef __attribute__((ext_vector_type(8))) short short8;
typedef __attribute__((ext_vector_type(4))) float f32x4;
typedef __attribute__((ext_vector_type(4))) int i32x4;

static __device__ __forceinline__ unsigned cvtpk(float lo, float hi) {
  __hip_bfloat162 h = __float22bfloat162_rn(make_float2(lo, hi));
  union { __hip_bfloat162 h; unsigned u; } v; v.h = h;
  return v.u;
}
static __device__ __forceinline__ short8 pack8(float4 f0, float4 f1) {
  union { i32x4 i; short8 s; } v;
  v.i.x = cvtpk(f0.x, f0.y);
  v.i.y = cvtpk(f0.z, f0.w);
  v.i.z = cvtpk(f1.x, f1.y);
  v.i.w = cvtpk(f1.z, f1.w);
  return v.s;
}
static __device__ __forceinline__ unsigned short f2bf(float f) {
  union { float f; unsigned u; } v; v.f = f;
  unsigned r = v.u + 0x7FFFu + ((v.u >> 16) & 1u);
  return (unsigned short)(r >> 16);
}
static __device__ __forceinline__ float bf2f(unsigned short u) {
  union { unsigned u; float f; } v; v.u = ((unsigned)u) << 16;
  return v.f;
}

// Phase-1 (agemm) and phase-2 (attn) LDS, unioned (alias-safe: see barriers).
struct P1 {
  char atile[64 * 256 * 2];          // 32 KB bf16 atom tile, XOR swizzle
  unsigned short sAT[256 * 68];      // 34 KB a^T tile (stride 68)
  float vp[4][256];                  // 4 KB v1 partials
};
struct P2 {
  unsigned short sattn[16 * 1024];   // 32 KB attn probs, XOR swizzle
  float ctxp[4][16][DD];             // 64 KB ctx partials (l-quarters)
};

// ---------------------------------------------------------------------------
// Fused kernel. Block i: x=i&7, k=i>>3, b=x+8*(k>>4), j=k&15.
// Phase 1: aT[b][e][l0..l0+64) + s2[b][l0..] (+ per-block v1/c0 redundantly).
// Sync:    cnt[b] += 1 (release); spin until ==16 (acquire).
// Phase 2: softmax rows n0..n0+16, PV MFMA from aT, LN, store.
// 1 block/CU (111 KB LDS) x 256 blocks -> all co-resident.
// ---------------------------------------------------------------------------
__global__ __launch_bounds__(1024, 4) void fused_kernel(
    const float* __restrict__ mol, const float* __restrict__ atom,
    const float* __restrict__ amask, const float* __restrict__ smask,
    const float* __restrict__ W_mol, const float* __restrict__ b_mol,
    const float* __restrict__ W_nb, const float* __restrict__ b_nb,
    const float* __restrict__ align_w, const float* __restrict__ align_b,
    const float* __restrict__ gamma, const float* __restrict__ beta,
    unsigned short* __restrict__ aT, float* __restrict__ s2g,
    unsigned int* __restrict__ cnt, float* __restrict__ outp) {
  __shared__ union { P1 p1; P2 p2; } sh;
  __shared__ float am_s[LL], sm_s[LL], s2_s[LL];
  __shared__ float v1s[256];
  __shared__ float s1s[16], mu_s[16], rs_s[16];
  __shared__ float c0s;

  int t = threadIdx.x, w = t >> 6, lane = t & 63;
  int i = blockIdx.x;
  int x = i & 7, k = i >> 3;
  int b = x + 8 * (k >> 4);          // all 32 blocks of b's pair on XCD b&7
  int j = k & 15;
  int l0 = j * 64;
  int n0 = j * 16;
  int lo16 = lane & 15, g = lane >> 4;

  // ---- stage atom tile -> LDS bf16 (swizzled) ----
  {
    int r = t >> 4, dseg = (t & 15) * 16;
    const float* src = atom + (size_t)(b * LL + l0 + r) * DD + dseg;
    #pragma unroll
    for (int q = 0; q < 2; ++q) {
      float4 f0 = *(const float4*)(src + q * 8);
      float4 f1 = *(const float4*)(src + q * 8 + 4);
      int byte = ((r * 256 + dseg + q * 8) * 2) ^ ((r & 7) << 4);
      *(short8*)(sh.p1.atile + byte) = pack8(f0, f1);
    }
  }
  // ---- stage masks (no dependency) ----
  if (t < 256) {
    *(float4*)&am_s[t * 4] = *(const float4*)&amask[b * LL + t * 4];
  } else if (t < 512) {
    int u = t - 256;
    *(float4*)&sm_s[u * 4] = *(const float4*)&smask[b * LL + u * 4];
  }
  // ---- v1 partials (redundant per block; W_mol is L2-hot) ----
  {
    int d = t & 255, eq = t >> 8;
    float acc = 0.f;
    #pragma unroll 8
    for (int e = eq * 64; e < eq * 64 + 64; ++e)
      acc += align_w[e] * W_mol[e * DD + d];
    sh.p1.vp[eq][d] = acc;
  }
  __syncthreads();  // B1: atile, vp, masks ready

  if (t < 256)
    v1s[t] = sh.p1.vp[0][t] + sh.p1.vp[1][t] + sh.p1.vp[2][t] + sh.p1.vp[3][t];
  if (w == 15) {
    float s = b_mol[lane] * align_w[lane] +
              b_mol[lane + 64] * align_w[lane + 64] +
              b_mol[lane + 128] * align_w[lane + 128] +
              b_mol[lane + 192] * align_w[lane + 192];
    #pragma unroll
    for (int off = 32; off > 0; off >>= 1) s += __shfl_xor(s, off, 64);
    if (lane == 0) c0s = s + align_b[0];
  }

  // ---- agemm MFMA: wave w -> e rows [w*16, w*16+16), 64 l from LDS ----
  {
    f32x4 acc[4];
    #pragma unroll
    for (int n = 0; n < 4; ++n) acc[n] = f32x4{0.f, 0.f, 0.f, 0.f};
    const float* Ap = W_nb + (size_t)(w * 16 + lo16) * DD + g * 8;
    #pragma unroll 4
    for (int kk = 0; kk < 8; ++kk) {
      float4 f0 = *(const float4*)(Ap + kk * 32);
      float4 f1 = *(const float4*)(Ap + kk * 32 + 4);
      short8 af = pack8(f0, f1);
      #pragma unroll
      for (int n = 0; n < 4; ++n) {
        int l = n * 16 + lo16;
        int byte = ((l * 256 + kk * 32 + g * 8) * 2) ^ ((l & 7) << 4);
        short8 bf = *(const short8*)(sh.p1.atile + byte);
        acc[n] = __builtin_amdgcn_mfma_f32_16x16x32_bf16(af, bf, acc[n], 0, 0, 0);
      }
    }
    // epilogue: +bias -> bf16 -> sAT
    int e_lo = w * 16 + g * 4;
    float4 bias = *(const float4*)&b_nb[e_lo];
    #pragma unroll
    for (int n = 0; n < 4; ++n) {
      int l = n * 16 + lo16;
      #pragma unroll
      for (int jj = 0; jj < 4; ++jj) {
        float v = acc[n][jj] + ((const float*)&bias)[jj];
        sh.p1.sAT[(e_lo + jj) * 68 + l] = f2bf(v);
      }
    }
  }
  __syncthreads();  // B2: sAT, v1s, c0s ready

  // ---- s2 from sAT + global stores ----
  {
    int l = t >> 4, ech = (t & 15) * 16;
    float s = 0.f;
    #pragma unroll 8
    for (int q = 0; q < 16; ++q) {
      int e = ech + q;
      s += align_w[DD + e] * bf2f(sh.p1.sAT[e * 68 + l]);
    }
    s += __shfl_xor(s, 1, 64);
    s += __shfl_xor(s, 2, 64);
    s += __shfl_xor(s, 4, 64);
    s += __shfl_xor(s, 8, 64);
    if ((t & 15) == 0) s2g[b * LL + l0 + l] = s;
  }
  {
    unsigned short* dst = aT + (size_t)b * DD * LL + l0;
    #pragma unroll
    for (int idx = t; idx < 4096; idx += 1024) {
      int e = idx >> 4, ch = idx & 15;
      ushort4 v = *(const ushort4*)&sh.p1.sAT[e * 68 + ch * 4];
      *(ushort4*)(dst + (size_t)e * LL + ch * 4) = v;
    }
  }
  // ---- s1 (independent of flag): wave w -> row w ----
  {
    const float* mr = mol + (size_t)(b * NN + n0 + w) * DD + lane * 4;
    float4 f = *(const float4*)mr;
    float s = f.x * v1s[lane * 4] + f.y * v1s[lane * 4 + 1] +
              f.z * v1s[lane * 4 + 2] + f.w * v1s[lane * 4 + 3];
    #pragma unroll
    for (int off = 32; off > 0; off >>= 1) s += __shfl_xor(s, off, 64);
    if (lane == 0) s1s[w] = s + c0s;
  }
  __syncthreads();  // B3: all global stores drained (vmcnt0 before barrier)

  // ---- per-b flag: release, count to 16, acquire ----
  if (t == 0) {
    __threadfence();
    atomicAdd(&cnt[b], 1u);
    while (__hip_atomic_load(&cnt[b], __ATOMIC_ACQUIRE,
                             __HIP_MEMORY_SCOPE_AGENT) < 16u) {
      __builtin_amdgcn_s_sleep(2);
    }
    __threadfence();
  }
  __syncthreads();  // B4: aT/s2 of all 16 producer blocks visible

  // ---- stage s2 ----
  if (t < 256) *(float4*)&s2_s[t * 4] = *(const float4*)&s2g[b * LL + t * 4];
  __syncthreads();  // B5

  // ---- softmax: wave w -> row w ----
  {
    int r = w;
    float s1v = s1s[r];
    float p[16];
    float mx = -INFINITY;
    #pragma unroll
    for (int q = 0; q < 16; ++q) {
      int l = lane + 64 * q;
      float sc = s1v + s2_s[l];
      sc = sc > 0.f ? sc : NEG_SLOPE * sc;
      sc += sm_s[l];
      p[q] = sc;
      mx = fmaxf(mx, sc);
    }
    #pragma unroll
    for (int off = 32; off > 0; off >>= 1) mx = fmaxf(mx, __shfl_xor(mx, off, 64));
    float sum = 0.f;
    #pragma unroll
    for (int q = 0; q < 16; ++q) {
      p[q] = __expf(p[q] - mx);
      sum += p[q];
    }
    #pragma unroll
    for (int off = 32; off > 0; off >>= 1) sum += __shfl_xor(sum, off, 64);
    float inv = 1.f / sum;
    #pragma unroll
    for (int q = 0; q < 16; ++q) {
      int l = lane + 64 * q;
      unsigned short bv = f2bf(p[q] * am_s[l] * inv);
      int byte = ((r * 1024 + l) * 2) ^ ((r & 7) << 4);
      *(unsigned short*)((char*)sh.p2.sattn + byte) = bv;
    }
  }
  __syncthreads();  // B6: sattn ready (aliases atile: last read before B2)

  // ---- PV MFMA: wave = e-quadrant (w&3) x l-quarter (w>>2) ----
  {
    int e0 = (w & 3) * 64, lq = w >> 2;
    f32x4 acc[4];
    #pragma unroll
    for (int n = 0; n < 4; ++n) acc[n] = f32x4{0.f, 0.f, 0.f, 0.f};
    const unsigned short* Bp =
        aT + (size_t)b * DD * LL + (size_t)(e0 + lo16) * LL + lq * 256 + g * 8;
    #pragma unroll 4
    for (int kk = 0; kk < 8; ++kk) {
      short8 afr = *(const short8*)((const char*)sh.p2.sattn +
          (((lo16 * 1024 + lq * 256 + kk * 32 + g * 8) * 2) ^ ((lo16 & 7) << 4)));
      #pragma unroll
      for (int n = 0; n < 4; ++n) {
        short8 bfr = *(const short8*)(Bp + (size_t)n * 16 * LL + kk * 32);
        acc[n] = __builtin_amdgcn_mfma_f32_16x16x32_bf16(afr, bfr, acc[n], 0, 0, 0);
      }
    }
    #pragma unroll
    for (int n = 0; n < 4; ++n)
      #pragma unroll
      for (int jj = 0; jj < 4; ++jj)
        sh.p2.ctxp[lq][g * 4 + jj][e0 + n * 16 + lo16] = acc[n][jj];
  }
  __syncthreads();  // B7: ctxp ready (aliases sAT: last read before B3)

  // ---- LN stats: wave w -> row w ----
  {
    int r = w;
    float s = 0.f, sq = 0.f;
    #pragma unroll
    for (int jj = 0; jj < 4; ++jj) {
      int cc = lane + 64 * jj;
      float v = sh.p2.ctxp[0][r][cc] + sh.p2.ctxp[1][r][cc] +
                sh.p2.ctxp[2][r][cc] + sh.p2.ctxp[3][r][cc];
      s += v;
      sq += v * v;
    }
    #pragma unroll
    for (int off = 32; off > 0; off >>= 1) {
      s += __shfl_xor(s, off, 64);
      sq += __shfl_xor(sq, off, 64);
    }
    if (lane == 0) {
      float mu = s * (1.f / 256.f);
      float var = sq * (1.f / 256.f) - mu * mu;
      mu_s[r] = mu;
      rs_s[r] = rsqrtf(var + LN_EPS);
    }
  }
  __syncthreads();  // B8

  // ---- store ----
  #pragma unroll
  for (int q = 0; q < 4; ++q) {
    int idx = t + 1024 * q;
    int r = idx >> 8, d = idx & 255;
    float v = sh.p2.ctxp[0][r][d] + sh.p2.ctxp[1][r][d] +
              sh.p2.ctxp[2][r][d] + sh.p2.ctxp[3][r][d];
    outp[(size_t)(b * NN + n0 + r) * DD + d] =
        (v - mu_s[r]) * rs_s[r] * gamma[d] + beta[d];
  }
}

// ---------------------------------------------------------------------------
extern "C" void kernel_launch(void* const* d_in, const int* in_sizes, int n_in,
                              void* d_out, int out_size, void* d_ws, size_t ws_size,
                              hipStream_t stream) {
  const float* mol     = (const float*)d_in[0];
  const float* atom    = (const float*)d_in[1];
  const float* amask   = (const float*)d_in[2];
  const float* smask   = (const float*)d_in[3];
  const float* W_mol   = (const float*)d_in[4];
  const float* b_mol   = (const float*)d_in[5];
  const float* W_nb    = (const float*)d_in[6];
  const float* b_nb    = (const float*)d_in[7];
  const float* align_w = (const float*)d_in[8];
  const float* align_b = (const float*)d_in[9];
  const float* gamma   = (const float*)d_in[10];
  const float* beta    = (const float*)d_in[11];
  float* outp = (float*)d_out;

  char* wsb = (char*)d_ws;
  unsigned short* aT = (unsigned short*)wsb;              // 8 MB
  float* s2g = (float*)(wsb + 8388608);                   // 64 KB
  unsigned int* cnt = (unsigned int*)(wsb + 8388608 + 65536);  // 64 B

  hipMemsetAsync(cnt, 0, 16 * sizeof(unsigned int), stream);
  fused_kernel<<<256, 1024, 0, stream>>>(mol, atom, amask, smask, W_mol, b_mol,
                                         W_nb, b_nb, align_w, align_b, gamma,
                                         beta, aT, s2g, cnt, outp);
}

// Round 8
// 55.219 us; speedup vs baseline: 1.3163x; 1.3163x over previous
//
#include <hip/hip_runtime.h>
#include <hip/hip_bf16.h>
#include <math.h>

#define BB 16
#define NN 256
#define LL 1024
#define DD 256

constexpr float LN_EPS = 1e-5f;
constexpr float NEG_SLOPE = 0.01f;

typedef __attribute__((ext_vector_type(8))) short short8;
typedef __attribute__((ext_vector_type(4))) float f32x4;
typedef __attribute__((ext_vector_type(4))) int i32x4;

static __device__ __forceinline__ unsigned cvtpk(float lo, float hi) {
  __hip_bfloat162 h = __float22bfloat162_rn(make_float2(lo, hi));
  union { __hip_bfloat162 h; unsigned u; } v; v.h = h;
  return v.u;
}
static __device__ __forceinline__ short8 pack8(float4 f0, float4 f1) {
  union { i32x4 i; short8 s; } v;
  v.i.x = cvtpk(f0.x, f0.y);
  v.i.y = cvtpk(f0.z, f0.w);
  v.i.z = cvtpk(f1.x, f1.y);
  v.i.w = cvtpk(f1.z, f1.w);
  return v.s;
}
static __device__ __forceinline__ unsigned short f2bf(float f) {
  union { float f; unsigned u; } v; v.f = f;
  unsigned r = v.u + 0x7FFFu + ((v.u >> 16) & 1u);
  return (unsigned short)(r >> 16);
}

// ---------------------------------------------------------------------------
// agemm (MFMA): aT[b][e][l] = sum_d W_nb[e,d]*atom[b,l,d] + b_nb[e]  (bf16)
//   + s2[b][l] computed from the f32 accumulators (register route, no LDS
//     read conflicts).
// 512 blocks x 512 thr (8 waves, 2 blocks/CU). Block tile 256e x 32l.
// Wave w: e in [w*32, w*32+32). Atom tile staged bf16 in LDS (XOR swizzle);
// W_nb loaded f32 in-loop (L2-hot), cvt_pk to bf16.
// XCD swizzle: all 32 blocks of batch b land on XCD b&7.
// ---------------------------------------------------------------------------
__global__ __launch_bounds__(512, 4) void agemm_kernel(
    const float* __restrict__ atom, const float* __restrict__ W_nb,
    const float* __restrict__ b_nb, const float* __restrict__ align_w,
    unsigned short* __restrict__ aT, float* __restrict__ s2g) {
  __shared__ char atile[32 * 256 * 2];        // 16 KB bf16, XOR-swizzled
  __shared__ unsigned short sAT[256 * 40];    // 20 KB (stride 40 shorts)
  __shared__ float s2p[8][32];                // 1 KB

  int t = threadIdx.x, w = t >> 6, lane = t & 63;
  int lo16 = lane & 15, g = lane >> 4;
  int i = blockIdx.x;
  int x = i & 7, k = i >> 3;          // k in 0..63
  int b = x + 8 * (k >> 5);           // 32 blocks per b, same XCD
  int l0 = (k & 31) * 32;

  // ---- stage atom tile -> LDS bf16 (swizzled) ----
  {
    int r = t >> 4, dseg = (t & 15) * 16;
    const float* src = atom + (size_t)(b * LL + l0 + r) * DD + dseg;
    #pragma unroll
    for (int q = 0; q < 2; ++q) {
      float4 f0 = *(const float4*)(src + q * 8);
      float4 f1 = *(const float4*)(src + q * 8 + 4);
      int byte = ((r * 256 + dseg + q * 8) * 2) ^ ((r & 7) << 4);
      *(short8*)(atile + byte) = pack8(f0, f1);
    }
  }
  __syncthreads();

  // ---- MFMA: wave w -> e rows [w*32, w*32+32), 32 l from LDS ----
  f32x4 acc[2][2];
  #pragma unroll
  for (int eg = 0; eg < 2; ++eg)
    #pragma unroll
    for (int lg = 0; lg < 2; ++lg) acc[eg][lg] = f32x4{0.f, 0.f, 0.f, 0.f};

  const float* Ap = W_nb + (size_t)(w * 32 + lo16) * DD + g * 8;
  #pragma unroll 2
  for (int kk = 0; kk < 8; ++kk) {
    short8 afk[2];
    #pragma unroll
    for (int eg = 0; eg < 2; ++eg) {
      float4 f0 = *(const float4*)(Ap + eg * 16 * DD + kk * 32);
      float4 f1 = *(const float4*)(Ap + eg * 16 * DD + kk * 32 + 4);
      afk[eg] = pack8(f0, f1);
    }
    short8 bfa[2];
    #pragma unroll
    for (int lg = 0; lg < 2; ++lg) {
      int l = lg * 16 + lo16;
      int byte = ((l * 256 + kk * 32 + g * 8) * 2) ^ ((l & 7) << 4);
      bfa[lg] = *(const short8*)(atile + byte);
    }
    #pragma unroll
    for (int eg = 0; eg < 2; ++eg)
      #pragma unroll
      for (int lg = 0; lg < 2; ++lg)
        acc[eg][lg] = __builtin_amdgcn_mfma_f32_16x16x32_bf16(
            afk[eg], bfa[lg], acc[eg][lg], 0, 0, 0);
  }

  // ---- epilogue: +bias -> sAT (bf16); s2 partials from registers ----
  float4 bias[2], w2r[2];
  #pragma unroll
  for (int eg = 0; eg < 2; ++eg) {
    bias[eg] = *(const float4*)&b_nb[w * 32 + eg * 16 + g * 4];
    w2r[eg] = *(const float4*)&align_w[DD + w * 32 + eg * 16 + g * 4];
  }
  float p0 = 0.f, p1 = 0.f;
  #pragma unroll
  for (int eg = 0; eg < 2; ++eg) {
    #pragma unroll
    for (int jj = 0; jj < 4; ++jj) {
      int e = w * 32 + eg * 16 + g * 4 + jj;
      float v0 = acc[eg][0][jj] + ((const float*)&bias[eg])[jj];
      float v1 = acc[eg][1][jj] + ((const float*)&bias[eg])[jj];
      sAT[e * 40 + lo16] = f2bf(v0);
      sAT[e * 40 + 16 + lo16] = f2bf(v1);
      p0 += ((const float*)&w2r[eg])[jj] * v0;
      p1 += ((const float*)&w2r[eg])[jj] * v1;
    }
  }
  p0 += __shfl_xor(p0, 16, 64); p0 += __shfl_xor(p0, 32, 64);
  p1 += __shfl_xor(p1, 16, 64); p1 += __shfl_xor(p1, 32, 64);
  if (g == 0) {
    s2p[w][lo16] = p0;
    s2p[w][16 + lo16] = p1;
  }
  __syncthreads();

  // ---- s2 store (conflict-free) ----
  if (t < 32) {
    float s = 0.f;
    #pragma unroll
    for (int q = 0; q < 8; ++q) s += s2p[q][t];
    s2g[b * LL + l0 + t] = s;
  }
  // ---- coalesced store to aT ----
  unsigned short* dst = aT + (size_t)b * DD * LL + l0;
  #pragma unroll
  for (int idx = t; idx < 2048; idx += 512) {
    int e = idx >> 3, ch = idx & 7;
    ushort4 v = *(const ushort4*)&sAT[e * 40 + ch * 4];
    *(ushort4*)(dst + (size_t)e * LL + ch * 4) = v;
  }
}

// ---------------------------------------------------------------------------
// attn: block = (b, 16 n-rows), 512 thr = 8 waves. XCD swizzle (b&7).
//  s1 via MFMA: x = mol_rows @ W_mol^T, s1[n] = sum_e w1[e]*(x[n,e]+b_mol[e]).
//  softmax (wave: 2 rows) -> bf16 LDS (XOR); PV MFMA split-K (e-quad x
//  l-half); LN + store.
// ---------------------------------------------------------------------------
__global__ __launch_bounds__(512) void attn_kernel(
    const unsigned short* __restrict__ aT, const float* __restrict__ mol,
    const float* __restrict__ W_mol, const float* __restrict__ b_mol,
    const float* __restrict__ align_w, const float* __restrict__ align_b,
    const float* __restrict__ s2g, const float* __restrict__ amask,
    const float* __restrict__ smask, const float* __restrict__ gamma,
    const float* __restrict__ beta, float* __restrict__ out) {
  __shared__ unsigned short sattn[16 * 1024];  // 32 KB, XOR-swizzled
  __shared__ float ctxp[2][16][DD];            // 32 KB
  __shared__ float s1p[8][16];
  __shared__ float s1s[16];
  __shared__ float mu_s[16], rs_s[16];
  int i = blockIdx.x;
  int x = i & 7, k = i >> 3;
  int b = x + 8 * (k >> 4);
  int n0 = (k & 15) * 16;
  int t = threadIdx.x, w = t >> 6, lane = t & 63;
  int lo16 = lane & 15, g = lane >> 4;

  // ---- s1 via MFMA: wave w -> e-slice [w*32, w*32+32) ----
  {
    f32x4 accx[2];
    accx[0] = f32x4{0.f, 0.f, 0.f, 0.f};
    accx[1] = f32x4{0.f, 0.f, 0.f, 0.f};
    const float* molp = mol + (size_t)(b * NN + n0 + lo16) * DD + g * 8;
    const float* wmp = W_mol + (size_t)(w * 32 + lo16) * DD + g * 8;
    #pragma unroll 2
    for (int kk = 0; kk < 8; ++kk) {
      float4 m0 = *(const float4*)(molp + kk * 32);
      float4 m1 = *(const float4*)(molp + kk * 32 + 4);
      short8 afm = pack8(m0, m1);
      #pragma unroll
      for (int eg = 0; eg < 2; ++eg) {
        float4 f0 = *(const float4*)(wmp + eg * 16 * DD + kk * 32);
        float4 f1 = *(const float4*)(wmp + eg * 16 * DD + kk * 32 + 4);
        short8 bfw = pack8(f0, f1);
        accx[eg] = __builtin_amdgcn_mfma_f32_16x16x32_bf16(afm, bfw,
                                                           accx[eg], 0, 0, 0);
      }
    }
    float q4[4] = {0.f, 0.f, 0.f, 0.f};
    #pragma unroll
    for (int eg = 0; eg < 2; ++eg) {
      int e = w * 32 + eg * 16 + lo16;
      float w1v = align_w[e], bmv = b_mol[e];
      #pragma unroll
      for (int jj = 0; jj < 4; ++jj) q4[jj] += w1v * (accx[eg][jj] + bmv);
    }
    #pragma unroll
    for (int m = 1; m <= 8; m <<= 1) {
      #pragma unroll
      for (int jj = 0; jj < 4; ++jj) q4[jj] += __shfl_xor(q4[jj], m, 64);
    }
    if (lo16 == 0) {
      #pragma unroll
      for (int jj = 0; jj < 4; ++jj) s1p[w][g * 4 + jj] = q4[jj];
    }
  }
  __syncthreads();
  if (t < 16) {
    float s = align_b[0];
    #pragma unroll
    for (int q = 0; q < 8; ++q) s += s1p[q][t];
    s1s[t] = s;
  }
  __syncthreads();

  // ---- softmax: wave w -> rows 2w, 2w+1 ----
  {
    float s2v[16], amv[16], smv[16];
    #pragma unroll
    for (int q = 0; q < 16; ++q) {
      int l = lane + 64 * q;
      s2v[q] = s2g[b * LL + l];
      amv[q] = amask[b * LL + l];
      smv[q] = smask[b * LL + l];
    }
    #pragma unroll
    for (int rr = 0; rr < 2; ++rr) {
      int r = w * 2 + rr;
      float s1v = s1s[r];
      float p[16];
      float mx = -INFINITY;
      #pragma unroll
      for (int q = 0; q < 16; ++q) {
        float sc = s1v + s2v[q];
        sc = sc > 0.f ? sc : NEG_SLOPE * sc;
        sc += smv[q];
        p[q] = sc;
        mx = fmaxf(mx, sc);
      }
      #pragma unroll
      for (int off = 32; off > 0; off >>= 1) mx = fmaxf(mx, __shfl_xor(mx, off, 64));
      float sum = 0.f;
      #pragma unroll
      for (int q = 0; q < 16; ++q) {
        p[q] = __expf(p[q] - mx);
        sum += p[q];
      }
      #pragma unroll
      for (int off = 32; off > 0; off >>= 1) sum += __shfl_xor(sum, off, 64);
      float inv = 1.f / sum;
      #pragma unroll
      for (int q = 0; q < 16; ++q) {
        unsigned short bv = f2bf(p[q] * amv[q] * inv);
        int l = lane + 64 * q;
        int byte = ((r * 1024 + l) * 2) ^ ((r & 7) << 4);
        *(unsigned short*)((char*)sattn + byte) = bv;
      }
    }
  }
  __syncthreads();

  // ---- PV MFMA: wave = e-quadrant (w&3) x l-half (w>>2) ----
  {
    int e0 = (w & 3) * 64, lh = w >> 2;
    f32x4 acc[4];
    #pragma unroll
    for (int n = 0; n < 4; ++n) acc[n] = f32x4{0.f, 0.f, 0.f, 0.f};
    const unsigned short* Bp =
        aT + (size_t)b * DD * LL + (size_t)(e0 + lo16) * LL + lh * 512 + g * 8;
    #pragma unroll 4
    for (int kk = 0; kk < 16; ++kk) {
      short8 afr = *(const short8*)((const char*)sattn +
          (((lo16 * 1024 + lh * 512 + kk * 32 + g * 8) * 2) ^ ((lo16 & 7) << 4)));
      #pragma unroll
      for (int n = 0; n < 4; ++n) {
        short8 bfr = *(const short8*)(Bp + (size_t)n * 16 * LL + kk * 32);
        acc[n] = __builtin_amdgcn_mfma_f32_16x16x32_bf16(afr, bfr, acc[n], 0, 0, 0);
      }
    }
    #pragma unroll
    for (int n = 0; n < 4; ++n)
      #pragma unroll
      for (int jj = 0; jj < 4; ++jj)
        ctxp[lh][g * 4 + jj][e0 + n * 16 + lo16] = acc[n][jj];
  }
  __syncthreads();

  // ---- LN stats: wave w -> rows 2w, 2w+1 ----
  #pragma unroll
  for (int rr = 0; rr < 2; ++rr) {
    int r = w * 2 + rr;
    float s = 0.f, sq = 0.f;
    #pragma unroll
    for (int jj = 0; jj < 4; ++jj) {
      int cc = lane + 64 * jj;
      float v = ctxp[0][r][cc] + ctxp[1][r][cc];
      s += v;
      sq += v * v;
    }
    #pragma unroll
    for (int off = 32; off > 0; off >>= 1) {
      s += __shfl_xor(s, off, 64);
      sq += __shfl_xor(sq, off, 64);
    }
    if (lane == 0) {
      float mu = s * (1.f / 256.f);
      float var = sq * (1.f / 256.f) - mu * mu;
      mu_s[r] = mu;
      rs_s[r] = rsqrtf(var + LN_EPS);
    }
  }
  __syncthreads();

  // ---- store ----
  #pragma unroll
  for (int q = 0; q < 8; ++q) {
    int idx = t + 512 * q;
    int r = idx >> 8, d = idx & 255;
    float v = ctxp[0][r][d] + ctxp[1][r][d];
    out[(size_t)(b * NN + n0 + r) * DD + d] =
        (v - mu_s[r]) * rs_s[r] * gamma[d] + beta[d];
  }
}

// ---------------------------------------------------------------------------
extern "C" void kernel_launch(void* const* d_in, const int* in_sizes, int n_in,
                              void* d_out, int out_size, void* d_ws, size_t ws_size,
                              hipStream_t stream) {
  const float* mol     = (const float*)d_in[0];
  const float* atom    = (const float*)d_in[1];
  const float* amask   = (const float*)d_in[2];
  const float* smask   = (const float*)d_in[3];
  const float* W_mol   = (const float*)d_in[4];
  const float* b_mol   = (const float*)d_in[5];
  const float* W_nb    = (const float*)d_in[6];
  const float* b_nb    = (const float*)d_in[7];
  const float* align_w = (const float*)d_in[8];
  const float* align_b = (const float*)d_in[9];
  const float* gamma   = (const float*)d_in[10];
  const float* beta    = (const float*)d_in[11];
  float* outp = (float*)d_out;

  char* wsb = (char*)d_ws;
  unsigned short* aT = (unsigned short*)wsb;          // 8 MB
  float* s2g = (float*)(wsb + 8388608);               // 64 KB

  agemm_kernel<<<512, 512, 0, stream>>>(atom, W_nb, b_nb, align_w, aT, s2g);
  attn_kernel<<<256, 512, 0, stream>>>(aT, mol, W_mol, b_mol, align_w,
                                       align_b, s2g, amask, smask, gamma,
                                       beta, outp);
}

// Round 9
// 46.787 us; speedup vs baseline: 1.5535x; 1.1802x over previous
//
#include <hip/hip_runtime.h>
#include <hip/hip_bf16.h>
#include <math.h>

#define BB 16
#define NN 256
#define LL 1024
#define DD 256

constexpr float LN_EPS = 1e-5f;
constexpr float NEG_SLOPE = 0.01f;

typedef __attribute__((ext_vector_type(8))) short short8;
typedef __attribute__((ext_vector_type(4))) float f32x4;
typedef __attribute__((ext_vector_type(4))) int i32x4;

static __device__ __forceinline__ unsigned cvtpk(float lo, float hi) {
  __hip_bfloat162 h = __float22bfloat162_rn(make_float2(lo, hi));
  union { __hip_bfloat162 h; unsigned u; } v; v.h = h;
  return v.u;
}
static __device__ __forceinline__ short8 pack8(float4 f0, float4 f1) {
  union { i32x4 i; short8 s; } v;
  v.i.x = cvtpk(f0.x, f0.y);
  v.i.y = cvtpk(f0.z, f0.w);
  v.i.z = cvtpk(f1.x, f1.y);
  v.i.w = cvtpk(f1.z, f1.w);
  return v.s;
}
static __device__ __forceinline__ unsigned short f2bf(float f) {
  union { float f; unsigned u; } v; v.f = f;
  unsigned r = v.u + 0x7FFFu + ((v.u >> 16) & 1u);
  return (unsigned short)(r >> 16);
}

// ---------------------------------------------------------------------------
// agemm (MFMA): aT[b][e][l] = sum_d W_nb[e,d]*atom[b,l,d] + b_nb[e]  (bf16)
//   + s2[b][l] from the f32 accumulators (register route, conflict-free)
//   + blocks 0..15 side-job: v1 columns; block 0: c0.
// 256 blocks x 512 thr (8 waves). Block tile 256e x 64l.
// Wave w: e0=(w&3)*64, l-half lsub=(w>>2)*32. Atom tile staged bf16 in LDS
// once (XOR swizzle). XCD swizzle: all blocks of batch b on XCD b&7.
// ---------------------------------------------------------------------------
__global__ __launch_bounds__(512) void agemm_kernel(
    const float* __restrict__ atom, const float* __restrict__ W_nb,
    const float* __restrict__ b_nb, const float* __restrict__ W_mol,
    const float* __restrict__ b_mol, const float* __restrict__ align_w,
    const float* __restrict__ align_b, unsigned short* __restrict__ aT,
    float* __restrict__ s2g, float* __restrict__ v1c) {
  __shared__ char atile[64 * 256 * 2];      // 32 KB bf16, XOR-swizzled
  __shared__ unsigned short sAT[256 * 68];  // 34 KB
  __shared__ float vp[32][16];
  __shared__ float s2p[8][34];              // padded, conflict-free

  int t = threadIdx.x;
  int w = t >> 6, lane = t & 63;
  int i = blockIdx.x;
  int x = i & 7, k = i >> 3;
  int b = x + 8 * (k >> 4);          // all blocks of b on XCD b&7
  int l0 = (k & 15) * 64;
  int lo16 = lane & 15, g = lane >> 4;

  // ---- stage atom tile -> LDS bf16 (swizzled) ----
  {
    int r = t >> 3, dseg = (t & 7) * 32;
    const float* src = atom + (size_t)(b * LL + l0 + r) * DD + dseg;
    #pragma unroll
    for (int q = 0; q < 4; ++q) {
      float4 f0 = *(const float4*)(src + q * 8);
      float4 f1 = *(const float4*)(src + q * 8 + 4);
      int byte = ((r * 256 + dseg + q * 8) * 2) ^ ((r & 7) << 4);
      *(short8*)(atile + byte) = pack8(f0, f1);
    }
  }

  // ---- side job: v1 columns (blocks 0..15), c0 (block 0) ----
  if (i < 16) {
    int d0 = i * 16;
    int dl = t & 15, eseg = t >> 4;
    float acc = 0.f;
    #pragma unroll
    for (int q = 0; q < 8; ++q) {
      int e = eseg * 8 + q;
      acc += align_w[e] * W_mol[e * DD + d0 + dl];
    }
    vp[eseg][dl] = acc;
    __syncthreads();
    if (t < 16) {
      float s = 0.f;
      #pragma unroll
      for (int q = 0; q < 32; ++q) s += vp[q][t];
      v1c[d0 + t] = s;
    }
    if (i == 0 && w == 1) {
      float s = b_mol[lane] * align_w[lane] +
                b_mol[lane + 64] * align_w[lane + 64] +
                b_mol[lane + 128] * align_w[lane + 128] +
                b_mol[lane + 192] * align_w[lane + 192];
      #pragma unroll
      for (int off = 32; off > 0; off >>= 1) s += __shfl_xor(s, off, 64);
      if (lane == 0) v1c[256] = s + align_b[0];
    }
  }
  __syncthreads();

  // ---- MFMA: wave w -> e in [e0, e0+64), l in [lsub, lsub+32) ----
  int e0 = (w & 3) * 64;
  int lsub = (w >> 2) * 32;

  f32x4 acc[4][2];
  #pragma unroll
  for (int m = 0; m < 4; ++m)
    #pragma unroll
    for (int n = 0; n < 2; ++n) acc[m][n] = f32x4{0.f, 0.f, 0.f, 0.f};

  const float* Ap = W_nb + (size_t)(e0 + lo16) * DD + g * 8;

  #pragma unroll 2
  for (int kk = 0; kk < 8; ++kk) {
    short8 af[4];
    #pragma unroll
    for (int m = 0; m < 4; ++m) {
      float4 f0 = *(const float4*)(Ap + m * 16 * DD + kk * 32);
      float4 f1 = *(const float4*)(Ap + m * 16 * DD + kk * 32 + 4);
      af[m] = pack8(f0, f1);
    }
    short8 bf[2];
    #pragma unroll
    for (int n = 0; n < 2; ++n) {
      int l = lsub + n * 16 + lo16;
      int byte = ((l * 256 + kk * 32 + g * 8) * 2) ^ ((l & 7) << 4);
      bf[n] = *(const short8*)(atile + byte);
    }
    #pragma unroll
    for (int m = 0; m < 4; ++m)
      #pragma unroll
      for (int n = 0; n < 2; ++n)
        acc[m][n] = __builtin_amdgcn_mfma_f32_16x16x32_bf16(af[m], bf[n],
                                                            acc[m][n], 0, 0, 0);
  }

  // ---- epilogue: +bias -> sAT (bf16); s2 partials from registers ----
  {
    float4 bias[4], w2r[4];
    #pragma unroll
    for (int m = 0; m < 4; ++m) {
      bias[m] = *(const float4*)&b_nb[e0 + m * 16 + g * 4];
      w2r[m] = *(const float4*)&align_w[DD + e0 + m * 16 + g * 4];
    }
    float p[2] = {0.f, 0.f};
    #pragma unroll
    for (int m = 0; m < 4; ++m) {
      #pragma unroll
      for (int n = 0; n < 2; ++n) {
        int l = lsub + n * 16 + lo16;
        #pragma unroll
        for (int jj = 0; jj < 4; ++jj) {
          float v = acc[m][n][jj] + ((const float*)&bias[m])[jj];
          sAT[(e0 + m * 16 + g * 4 + jj) * 68 + l] = f2bf(v);
          p[n] += ((const float*)&w2r[m])[jj] * v;
        }
      }
    }
    #pragma unroll
    for (int n = 0; n < 2; ++n) {
      p[n] += __shfl_xor(p[n], 16, 64);
      p[n] += __shfl_xor(p[n], 32, 64);
    }
    if (g == 0) {
      s2p[w][lo16] = p[0];
      s2p[w][16 + lo16] = p[1];
    }
  }
  __syncthreads();

  // ---- s2 final sum (conflict-free) + store ----
  if (t < 64) {
    int wh = (t >> 5) * 4;          // wave group covering this l-half
    int li = t & 31;
    float s = s2p[wh][li] + s2p[wh + 1][li] + s2p[wh + 2][li] + s2p[wh + 3][li];
    s2g[b * LL + l0 + t] = s;
  }
  // ---- coalesced store to aT ----
  unsigned short* dst = aT + (size_t)b * DD * LL + l0;
  #pragma unroll
  for (int idx = t; idx < 4096; idx += 512) {
    int e = idx >> 4, ch = idx & 15;
    ushort4 v = *(const ushort4*)&sAT[e * 68 + ch * 4];
    *(ushort4*)(dst + (size_t)e * LL + ch * 4) = v;
  }
}

// ---------------------------------------------------------------------------
// attn: block = (b, 16 n-rows), 512 thr = 8 waves. XCD swizzle (b&7).
//  s1 in-block from mol & v1 (32 thr/row); s2/masks staged once in LDS;
//  softmax (wave: 2 rows) -> bf16 LDS (XOR); PV MFMA split-K (e-quad x
//  l-half); LN + store.
// ---------------------------------------------------------------------------
__global__ __launch_bounds__(512) void attn_kernel(
    const unsigned short* __restrict__ aT, const float* __restrict__ mol,
    const float* __restrict__ v1c, const float* __restrict__ s2g,
    const float* __restrict__ amask, const float* __restrict__ smask,
    const float* __restrict__ gamma, const float* __restrict__ beta,
    float* __restrict__ out) {
  __shared__ unsigned short sattn[16 * 1024];  // 32 KB, XOR-swizzled
  __shared__ float ctxp[2][16][DD];            // 32 KB
  __shared__ float s2_s[LL], am_s[LL], sm_s[LL];  // 12 KB
  __shared__ float v1s[256];
  __shared__ float s1s[16];
  __shared__ float mu_s[16], rs_s[16];
  int i = blockIdx.x;
  int x = i & 7, k = i >> 3;
  int b = x + 8 * (k >> 4);
  int n0 = (k & 15) * 16;
  int t = threadIdx.x, w = t >> 6, lane = t & 63;

  float c0 = v1c[256];
  if (t < 256) v1s[t] = v1c[t];
  // ---- stage s2/masks once (coalesced float4) ----
  if (t < 256) {
    *(float4*)&s2_s[t * 4] = *(const float4*)&s2g[b * LL + t * 4];
  } else {
    int u = t - 256;
    *(float4*)&am_s[u * 4] = *(const float4*)&amask[b * LL + u * 4];
  }
  if (t < 256) {
    *(float4*)&sm_s[t * 4] = *(const float4*)&smask[b * LL + t * 4];
  }
  __syncthreads();

  // ---- s1: 32 thr/row ----
  {
    int r = t >> 5, off = (t & 31) * 8;
    const float* mr = mol + (size_t)(b * NN + n0 + r) * DD + off;
    float s = 0.f;
    #pragma unroll
    for (int q = 0; q < 2; ++q) {
      float4 f = *(const float4*)(mr + q * 4);
      s += f.x * v1s[off + q * 4] + f.y * v1s[off + q * 4 + 1] +
           f.z * v1s[off + q * 4 + 2] + f.w * v1s[off + q * 4 + 3];
    }
    s += __shfl_xor(s, 1, 64);
    s += __shfl_xor(s, 2, 64);
    s += __shfl_xor(s, 4, 64);
    s += __shfl_xor(s, 8, 64);
    s += __shfl_xor(s, 16, 64);
    if ((t & 31) == 0) s1s[r] = s + c0;
  }
  __syncthreads();

  // ---- softmax: wave w -> rows 2w, 2w+1 (reads from LDS) ----
  {
    #pragma unroll
    for (int rr = 0; rr < 2; ++rr) {
      int r = w * 2 + rr;
      float s1v = s1s[r];
      float p[16];
      float mx = -INFINITY;
      #pragma unroll
      for (int q = 0; q < 16; ++q) {
        int l = lane + 64 * q;
        float sc = s1v + s2_s[l];
        sc = sc > 0.f ? sc : NEG_SLOPE * sc;
        sc += sm_s[l];
        p[q] = sc;
        mx = fmaxf(mx, sc);
      }
      #pragma unroll
      for (int off = 32; off > 0; off >>= 1) mx = fmaxf(mx, __shfl_xor(mx, off, 64));
      float sum = 0.f;
      #pragma unroll
      for (int q = 0; q < 16; ++q) {
        p[q] = __expf(p[q] - mx);
        sum += p[q];
      }
      #pragma unroll
      for (int off = 32; off > 0; off >>= 1) sum += __shfl_xor(sum, off, 64);
      float inv = 1.f / sum;
      #pragma unroll
      for (int q = 0; q < 16; ++q) {
        int l = lane + 64 * q;
        unsigned short bv = f2bf(p[q] * am_s[l] * inv);
        int byte = ((r * 1024 + l) * 2) ^ ((r & 7) << 4);
        *(unsigned short*)((char*)sattn + byte) = bv;
      }
    }
  }
  __syncthreads();

  // ---- PV MFMA: wave = e-quadrant (w&3) x l-half (w>>2) ----
  int lo16 = lane & 15, g = lane >> 4;
  {
    int e0 = (w & 3) * 64, lh = w >> 2;
    f32x4 acc[4];
    #pragma unroll
    for (int n = 0; n < 4; ++n) acc[n] = f32x4{0.f, 0.f, 0.f, 0.f};
    const unsigned short* Bp =
        aT + (size_t)b * DD * LL + (size_t)(e0 + lo16) * LL + lh * 512 + g * 8;
    #pragma unroll 4
    for (int kk = 0; kk < 16; ++kk) {
      short8 afr = *(const short8*)((const char*)sattn +
          (((lo16 * 1024 + lh * 512 + kk * 32 + g * 8) * 2) ^ ((lo16 & 7) << 4)));
      #pragma unroll
      for (int n = 0; n < 4; ++n) {
        short8 bfr = *(const short8*)(Bp + (size_t)n * 16 * LL + kk * 32);
        acc[n] = __builtin_amdgcn_mfma_f32_16x16x32_bf16(afr, bfr, acc[n], 0, 0, 0);
      }
    }
    #pragma unroll
    for (int n = 0; n < 4; ++n)
      #pragma unroll
      for (int jj = 0; jj < 4; ++jj)
        ctxp[lh][g * 4 + jj][e0 + n * 16 + lo16] = acc[n][jj];
  }
  __syncthreads();

  // ---- LN stats: wave w -> rows 2w, 2w+1 ----
  #pragma unroll
  for (int rr = 0; rr < 2; ++rr) {
    int r = w * 2 + rr;
    float s = 0.f, sq = 0.f;
    #pragma unroll
    for (int jj = 0; jj < 4; ++jj) {
      int cc = lane + 64 * jj;
      float v = ctxp[0][r][cc] + ctxp[1][r][cc];
      s += v;
      sq += v * v;
    }
    #pragma unroll
    for (int off = 32; off > 0; off >>= 1) {
      s += __shfl_xor(s, off, 64);
      sq += __shfl_xor(sq, off, 64);
    }
    if (lane == 0) {
      float mu = s * (1.f / 256.f);
      float var = sq * (1.f / 256.f) - mu * mu;
      mu_s[r] = mu;
      rs_s[r] = rsqrtf(var + LN_EPS);
    }
  }
  __syncthreads();

  // ---- store ----
  #pragma unroll
  for (int q = 0; q < 8; ++q) {
    int idx = t + 512 * q;
    int r = idx >> 8, d = idx & 255;
    float v = ctxp[0][r][d] + ctxp[1][r][d];
    out[(size_t)(b * NN + n0 + r) * DD + d] =
        (v - mu_s[r]) * rs_s[r] * gamma[d] + beta[d];
  }
}

// ---------------------------------------------------------------------------
extern "C" void kernel_launch(void* const* d_in, const int* in_sizes, int n_in,
                              void* d_out, int out_size, void* d_ws, size_t ws_size,
                              hipStream_t stream) {
  const float* mol     = (const float*)d_in[0];
  const float* atom    = (const float*)d_in[1];
  const float* amask   = (const float*)d_in[2];
  const float* smask   = (const float*)d_in[3];
  const float* W_mol   = (const float*)d_in[4];
  const float* b_mol   = (const float*)d_in[5];
  const float* W_nb    = (const float*)d_in[6];
  const float* b_nb    = (const float*)d_in[7];
  const float* align_w = (const float*)d_in[8];
  const float* align_b = (const float*)d_in[9];
  const float* gamma   = (const float*)d_in[10];
  const float* beta    = (const float*)d_in[11];
  float* outp = (float*)d_out;

  char* wsb = (char*)d_ws;
  unsigned short* aT = (unsigned short*)wsb;          // 8 MB
  float* s2g = (float*)(wsb + 8388608);               // 64 KB
  float* v1c = s2g + BB * LL;                         // 257 floats

  agemm_kernel<<<256, 512, 0, stream>>>(atom, W_nb, b_nb, W_mol, b_mol,
                                        align_w, align_b, aT, s2g, v1c);
  attn_kernel<<<256, 512, 0, stream>>>(aT, mol, v1c, s2g, amask, smask,
                                       gamma, beta, outp);
}

// Round 10
// 39.302 us; speedup vs baseline: 1.8494x; 1.1904x over previous
//
#include <hip/hip_runtime.h>
#include <hip/hip_bf16.h>
#include <math.h>

#define BB 16
#define NN 256
#define LL 1024
#define DD 256

constexpr float LN_EPS = 1e-5f;
constexpr float NEG_SLOPE = 0.01f;

typedef __attribute__((ext_vector_type(8))) short short8;
typedef __attribute__((ext_vector_type(4))) float f32x4;
typedef __attribute__((ext_vector_type(4))) int i32x4;

static __device__ __forceinline__ unsigned cvtpk(float lo, float hi) {
  __hip_bfloat162 h = __float22bfloat162_rn(make_float2(lo, hi));
  union { __hip_bfloat162 h; unsigned u; } v; v.h = h;
  return v.u;
}
static __device__ __forceinline__ short8 pack8(float4 f0, float4 f1) {
  union { i32x4 i; short8 s; } v;
  v.i.x = cvtpk(f0.x, f0.y);
  v.i.y = cvtpk(f0.z, f0.w);
  v.i.z = cvtpk(f1.x, f1.y);
  v.i.w = cvtpk(f1.z, f1.w);
  return v.s;
}
static __device__ __forceinline__ unsigned short f2bf(float f) {
  union { float f; unsigned u; } v; v.f = f;
  unsigned r = v.u + 0x7FFFu + ((v.u >> 16) & 1u);
  return (unsigned short)(r >> 16);
}

// ---------------------------------------------------------------------------
// agemm (MFMA): aT[b][e][l] = sum_d W_nb[e,d]*atom[b,l,d] + b_nb[e]  (bf16)
//   + s2[b][l] from the f32 accumulators (register route, conflict-free)
//   + blocks 0..15 side-job: v1 columns; block 0: c0.
// 256 blocks x 512 thr (8 waves). Block tile 256e x 64l.
// Wave w: e in [w*32, w*32+32), ALL 64 l (W_nb read exactly once per block).
// Atom tile staged bf16 in LDS once (XOR swizzle).
// XCD swizzle: all blocks of batch b on XCD b&7.
// ---------------------------------------------------------------------------
__global__ __launch_bounds__(512) void agemm_kernel(
    const float* __restrict__ atom, const float* __restrict__ W_nb,
    const float* __restrict__ b_nb, const float* __restrict__ W_mol,
    const float* __restrict__ b_mol, const float* __restrict__ align_w,
    const float* __restrict__ align_b, unsigned short* __restrict__ aT,
    float* __restrict__ s2g, float* __restrict__ v1c) {
  __shared__ char atile[64 * 256 * 2];      // 32 KB bf16, XOR-swizzled
  __shared__ unsigned short sAT[256 * 68];  // 34 KB
  __shared__ float vp[32][16];
  __shared__ float s2p[8][66];              // padded, conflict-free

  int t = threadIdx.x;
  int w = t >> 6, lane = t & 63;
  int i = blockIdx.x;
  int x = i & 7, k = i >> 3;
  int b = x + 8 * (k >> 4);          // all blocks of b on XCD b&7
  int l0 = (k & 15) * 64;
  int lo16 = lane & 15, g = lane >> 4;

  // ---- stage atom tile -> LDS bf16 (swizzled) ----
  {
    int r = t >> 3, dseg = (t & 7) * 32;
    const float* src = atom + (size_t)(b * LL + l0 + r) * DD + dseg;
    #pragma unroll
    for (int q = 0; q < 4; ++q) {
      float4 f0 = *(const float4*)(src + q * 8);
      float4 f1 = *(const float4*)(src + q * 8 + 4);
      int byte = ((r * 256 + dseg + q * 8) * 2) ^ ((r & 7) << 4);
      *(short8*)(atile + byte) = pack8(f0, f1);
    }
  }

  // ---- side job: v1 columns (blocks 0..15), c0 (block 0) ----
  if (i < 16) {
    int d0 = i * 16;
    int dl = t & 15, eseg = t >> 4;
    float acc = 0.f;
    #pragma unroll
    for (int q = 0; q < 8; ++q) {
      int e = eseg * 8 + q;
      acc += align_w[e] * W_mol[e * DD + d0 + dl];
    }
    vp[eseg][dl] = acc;
    __syncthreads();
    if (t < 16) {
      float s = 0.f;
      #pragma unroll
      for (int q = 0; q < 32; ++q) s += vp[q][t];
      v1c[d0 + t] = s;
    }
    if (i == 0 && w == 1) {
      float s = b_mol[lane] * align_w[lane] +
                b_mol[lane + 64] * align_w[lane + 64] +
                b_mol[lane + 128] * align_w[lane + 128] +
                b_mol[lane + 192] * align_w[lane + 192];
      #pragma unroll
      for (int off = 32; off > 0; off >>= 1) s += __shfl_xor(s, off, 64);
      if (lane == 0) v1c[256] = s + align_b[0];
    }
  }
  __syncthreads();

  // ---- MFMA: wave w -> e rows [w*32, w*32+32), all 64 l from LDS ----
  f32x4 acc[2][4];
  #pragma unroll
  for (int m = 0; m < 2; ++m)
    #pragma unroll
    for (int n = 0; n < 4; ++n) acc[m][n] = f32x4{0.f, 0.f, 0.f, 0.f};

  const float* Ap = W_nb + (size_t)(w * 32 + lo16) * DD + g * 8;

  #pragma unroll 2
  for (int kk = 0; kk < 8; ++kk) {
    short8 af[2];
    #pragma unroll
    for (int m = 0; m < 2; ++m) {
      float4 f0 = *(const float4*)(Ap + m * 16 * DD + kk * 32);
      float4 f1 = *(const float4*)(Ap + m * 16 * DD + kk * 32 + 4);
      af[m] = pack8(f0, f1);
    }
    short8 bf[4];
    #pragma unroll
    for (int n = 0; n < 4; ++n) {
      int l = n * 16 + lo16;
      int byte = ((l * 256 + kk * 32 + g * 8) * 2) ^ ((l & 7) << 4);
      bf[n] = *(const short8*)(atile + byte);
    }
    #pragma unroll
    for (int m = 0; m < 2; ++m)
      #pragma unroll
      for (int n = 0; n < 4; ++n)
        acc[m][n] = __builtin_amdgcn_mfma_f32_16x16x32_bf16(af[m], bf[n],
                                                            acc[m][n], 0, 0, 0);
  }

  // ---- epilogue: +bias -> sAT (bf16); s2 partials from registers ----
  {
    float4 bias[2], w2r[2];
    #pragma unroll
    for (int m = 0; m < 2; ++m) {
      bias[m] = *(const float4*)&b_nb[w * 32 + m * 16 + g * 4];
      w2r[m] = *(const float4*)&align_w[DD + w * 32 + m * 16 + g * 4];
    }
    float p[4] = {0.f, 0.f, 0.f, 0.f};
    #pragma unroll
    for (int m = 0; m < 2; ++m) {
      #pragma unroll
      for (int n = 0; n < 4; ++n) {
        int l = n * 16 + lo16;
        #pragma unroll
        for (int jj = 0; jj < 4; ++jj) {
          float v = acc[m][n][jj] + ((const float*)&bias[m])[jj];
          sAT[(w * 32 + m * 16 + g * 4 + jj) * 68 + l] = f2bf(v);
          p[n] += ((const float*)&w2r[m])[jj] * v;
        }
      }
    }
    #pragma unroll
    for (int n = 0; n < 4; ++n) {
      p[n] += __shfl_xor(p[n], 16, 64);
      p[n] += __shfl_xor(p[n], 32, 64);
    }
    if (g == 0) {
      #pragma unroll
      for (int n = 0; n < 4; ++n) s2p[w][n * 16 + lo16] = p[n];
    }
  }
  __syncthreads();

  // ---- s2 final sum over 8 waves (conflict-free) + store ----
  if (t < 64) {
    float s = 0.f;
    #pragma unroll
    for (int q = 0; q < 8; ++q) s += s2p[q][t];
    s2g[b * LL + l0 + t] = s;
  }
  // ---- coalesced store to aT ----
  unsigned short* dst = aT + (size_t)b * DD * LL + l0;
  #pragma unroll
  for (int idx = t; idx < 4096; idx += 512) {
    int e = idx >> 4, ch = idx & 15;
    ushort4 v = *(const ushort4*)&sAT[e * 68 + ch * 4];
    *(ushort4*)(dst + (size_t)e * LL + ch * 4) = v;
  }
}

// ---------------------------------------------------------------------------
// attn: block = (b, 16 n-rows), 512 thr = 8 waves. XCD swizzle (b&7).
// (Byte-identical to the 40.8 µs version.)
// ---------------------------------------------------------------------------
__global__ __launch_bounds__(512) void attn_kernel(
    const unsigned short* __restrict__ aT, const float* __restrict__ mol,
    const float* __restrict__ v1c, const float* __restrict__ s2,
    const float* __restrict__ amask, const float* __restrict__ smask,
    const float* __restrict__ gamma, const float* __restrict__ beta,
    float* __restrict__ out) {
  __shared__ unsigned short sattn[16 * 1024];  // 32 KB, XOR-swizzled
  __shared__ float ctxp[2][16][DD];            // 32 KB
  __shared__ float v1s[256];
  __shared__ float s1s[16];
  __shared__ float mu_s[16], rs_s[16];
  int i = blockIdx.x;
  int x = i & 7, k = i >> 3;
  int b = x + 8 * (k >> 4);
  int n0 = (k & 15) * 16;
  int t = threadIdx.x, w = t >> 6, lane = t & 63;

  float c0 = v1c[256];
  if (t < 256) v1s[t] = v1c[t];
  __syncthreads();

  // ---- s1: 32 thr/row ----
  {
    int r = t >> 5, off = (t & 31) * 8;
    const float* mr = mol + (size_t)(b * NN + n0 + r) * DD + off;
    float s = 0.f;
    #pragma unroll
    for (int q = 0; q < 2; ++q) {
      float4 f = *(const float4*)(mr + q * 4);
      s += f.x * v1s[off + q * 4] + f.y * v1s[off + q * 4 + 1] +
           f.z * v1s[off + q * 4 + 2] + f.w * v1s[off + q * 4 + 3];
    }
    s += __shfl_xor(s, 1, 64);
    s += __shfl_xor(s, 2, 64);
    s += __shfl_xor(s, 4, 64);
    s += __shfl_xor(s, 8, 64);
    s += __shfl_xor(s, 16, 64);
    if ((t & 31) == 0) s1s[r] = s + c0;
  }
  __syncthreads();

  // ---- softmax: wave w -> rows 2w, 2w+1 ----
  {
    float s2v[16], amv[16], smv[16];
    #pragma unroll
    for (int q = 0; q < 16; ++q) {
      int l = lane + 64 * q;
      s2v[q] = s2[b * LL + l];
      amv[q] = amask[b * LL + l];
      smv[q] = smask[b * LL + l];
    }
    #pragma unroll
    for (int rr = 0; rr < 2; ++rr) {
      int r = w * 2 + rr;
      float s1v = s1s[r];
      float p[16];
      float mx = -INFINITY;
      #pragma unroll
      for (int q = 0; q < 16; ++q) {
        float sc = s1v + s2v[q];
        sc = sc > 0.f ? sc : NEG_SLOPE * sc;
        sc += smv[q];
        p[q] = sc;
        mx = fmaxf(mx, sc);
      }
      #pragma unroll
      for (int off = 32; off > 0; off >>= 1) mx = fmaxf(mx, __shfl_xor(mx, off, 64));
      float sum = 0.f;
      #pragma unroll
      for (int q = 0; q < 16; ++q) {
        p[q] = __expf(p[q] - mx);
        sum += p[q];
      }
      #pragma unroll
      for (int off = 32; off > 0; off >>= 1) sum += __shfl_xor(sum, off, 64);
      float inv = 1.f / sum;
      #pragma unroll
      for (int q = 0; q < 16; ++q) {
        unsigned short bv = f2bf(p[q] * amv[q] * inv);
        int l = lane + 64 * q;
        int byte = ((r * 1024 + l) * 2) ^ ((r & 7) << 4);
        *(unsigned short*)((char*)sattn + byte) = bv;
      }
    }
  }
  __syncthreads();

  // ---- PV MFMA: wave = e-quadrant (w&3) x l-half (w>>2) ----
  int lo16 = lane & 15, g = lane >> 4;
  {
    int e0 = (w & 3) * 64, lh = w >> 2;
    f32x4 acc[4];
    #pragma unroll
    for (int n = 0; n < 4; ++n) acc[n] = f32x4{0.f, 0.f, 0.f, 0.f};
    const unsigned short* Bp =
        aT + (size_t)b * DD * LL + (size_t)(e0 + lo16) * LL + lh * 512 + g * 8;
    #pragma unroll 4
    for (int kk = 0; kk < 16; ++kk) {
      short8 afr = *(const short8*)((const char*)sattn +
          (((lo16 * 1024 + lh * 512 + kk * 32 + g * 8) * 2) ^ ((lo16 & 7) << 4)));
      #pragma unroll
      for (int n = 0; n < 4; ++n) {
        short8 bfr = *(const short8*)(Bp + (size_t)n * 16 * LL + kk * 32);
        acc[n] = __builtin_amdgcn_mfma_f32_16x16x32_bf16(afr, bfr, acc[n], 0, 0, 0);
      }
    }
    #pragma unroll
    for (int n = 0; n < 4; ++n)
      #pragma unroll
      for (int jj = 0; jj < 4; ++jj)
        ctxp[lh][g * 4 + jj][e0 + n * 16 + lo16] = acc[n][jj];
  }
  __syncthreads();

  // ---- LN stats: wave w -> rows 2w, 2w+1 ----
  #pragma unroll
  for (int rr = 0; rr < 2; ++rr) {
    int r = w * 2 + rr;
    float s = 0.f, sq = 0.f;
    #pragma unroll
    for (int jj = 0; jj < 4; ++jj) {
      int cc = lane + 64 * jj;
      float v = ctxp[0][r][cc] + ctxp[1][r][cc];
      s += v;
      sq += v * v;
    }
    #pragma unroll
    for (int off = 32; off > 0; off >>= 1) {
      s += __shfl_xor(s, off, 64);
      sq += __shfl_xor(sq, off, 64);
    }
    if (lane == 0) {
      float mu = s * (1.f / 256.f);
      float var = sq * (1.f / 256.f) - mu * mu;
      mu_s[r] = mu;
      rs_s[r] = rsqrtf(var + LN_EPS);
    }
  }
  __syncthreads();

  // ---- store ----
  #pragma unroll
  for (int q = 0; q < 8; ++q) {
    int idx = t + 512 * q;
    int r = idx >> 8, d = idx & 255;
    float v = ctxp[0][r][d] + ctxp[1][r][d];
    out[(size_t)(b * NN + n0 + r) * DD + d] =
        (v - mu_s[r]) * rs_s[r] * gamma[d] + beta[d];
  }
}

// ---------------------------------------------------------------------------
extern "C" void kernel_launch(void* const* d_in, const int* in_sizes, int n_in,
                              void* d_out, int out_size, void* d_ws, size_t ws_size,
                              hipStream_t stream) {
  const float* mol     = (const float*)d_in[0];
  const float* atom    = (const float*)d_in[1];
  const float* amask   = (const float*)d_in[2];
  const float* smask   = (const float*)d_in[3];
  const float* W_mol   = (const float*)d_in[4];
  const float* b_mol   = (const float*)d_in[5];
  const float* W_nb    = (const float*)d_in[6];
  const float* b_nb    = (const float*)d_in[7];
  const float* align_w = (const float*)d_in[8];
  const float* align_b = (const float*)d_in[9];
  const float* gamma   = (const float*)d_in[10];
  const float* beta    = (const float*)d_in[11];
  float* outp = (float*)d_out;

  char* wsb = (char*)d_ws;
  unsigned short* aT = (unsigned short*)wsb;          // 8 MB
  float* s2g = (float*)(wsb + 8388608);               // 64 KB
  float* v1c = s2g + BB * LL;                         // 257 floats

  agemm_kernel<<<256, 512, 0, stream>>>(atom, W_nb, b_nb, W_mol, b_mol,
                                        align_w, align_b, aT, s2g, v1c);
  attn_kernel<<<256, 512, 0, stream>>>(aT, mol, v1c, s2g, amask, smask,
                                       gamma, beta, outp);
}